// Round 1
// baseline (614.235 us; speedup 1.0000x reference)
//
#include <hip/hip_runtime.h>

typedef unsigned short u16;
typedef unsigned int u32;
typedef unsigned long long u64;

#define B_   16
#define C_   384
#define H_   28
#define W_   28
#define S_   784
#define NH_  6
#define HD_  64
#define BS_  (B_ * S_)            // 12544
#define SCALE_ 0.05103103630798288f  // 384^-0.5
#define EPS_ 1e-5f

typedef __attribute__((ext_vector_type(8))) short bf16x8;
typedef __attribute__((ext_vector_type(4))) float f32x4;

__device__ __forceinline__ float bf2f(u16 u) {
    return __uint_as_float(((u32)u) << 16);
}
__device__ __forceinline__ u16 f2bf(float f) {
    u32 x = __float_as_uint(f);
    u32 r = (x + 0x7fffu + ((x >> 16) & 1u)) >> 16;   // RNE
    return (u16)r;
}

// ---------------------------------------------------------------------------
// Kernel 2 (fused, 9-in-1): depthwise 3x3 conv for ALL 9 idx branches per
// block. One block = (h row, batch, w-half); loads the x1/x2 sliding windows
// once and feeds all 9 weight sets (idx 0-2: x1, 3-5: x2, 6-8: x1+x2).
// Cuts input HBM fetch ~6x (was 215 MB: each of 9 branches re-streamed its
// image) and hides load latency behind ~90 FMA per load round instead of 9.
// BN partial sums via atomicAdd into part[idx][c][2] (pre-zeroed).
// y[idx][b][s][c] bf16. Stats accumulated on pre-rounding f32.
// __launch_bounds__(384,3): cap VGPR at 170 -> 2 blocks/CU (12 waves).
// ---------------------------------------------------------------------------
__launch_bounds__(384, 3)
__global__ void k_conv(const float* __restrict__ x1, const float* __restrict__ x2,
                       const float* __restrict__ dw, u16* __restrict__ y,
                       float* __restrict__ part) {
    int c = threadIdx.x;            // 0..383
    int h = blockIdx.x;             // 0..27
    int b = blockIdx.y;             // 0..15
    int w0 = blockIdx.z * 14;       // 0 or 14 (w-half split for balance)
    const float* pa = x1 + (size_t)b * S_ * C_ + c;
    const float* pb = x2 + (size_t)b * S_ * C_ + c;

    float wt[9][9];
#pragma unroll
    for (int i = 0; i < 9; ++i)
#pragma unroll
        for (int t = 0; t < 9; ++t)
            wt[i][t] = dw[(i * C_ + c) * 9 + t];

    // sliding windows for x1 and x2; x1+x2 taps computed on the fly (regs)
    float a1[3][3], a2[3][3];
#pragma unroll
    for (int dh = 0; dh < 3; ++dh) {
        int hh = h + dh - 1;
        bool hv = (hh >= 0) && (hh < H_);
#pragma unroll
        for (int j = 0; j < 3; ++j) {
            int ww = w0 - 1 + j;
            float v1 = 0.f, v2 = 0.f;
            if (hv && ww >= 0) {        // right edge safe: w0+1 <= 15 < 28
                size_t off = (size_t)(hh * W_ + ww) * C_;
                v1 = pa[off]; v2 = pb[off];
            }
            a1[dh][j] = v1; a2[dh][j] = v2;
        }
    }

    u16* dst[9];
#pragma unroll
    for (int i = 0; i < 9; ++i)
        dst[i] = y + ((size_t)(i * B_ + b) * S_ + h * W_ + w0) * C_ + c;

    float sum[9], sq[9];
#pragma unroll
    for (int i = 0; i < 9; ++i) { sum[i] = 0.f; sq[i] = 0.f; }

    for (int w = 0; w < 14; ++w) {
        float t3[9];
#pragma unroll
        for (int dh = 0; dh < 3; ++dh)
#pragma unroll
            for (int j = 0; j < 3; ++j)
                t3[dh * 3 + j] = a1[dh][j] + a2[dh][j];
#pragma unroll
        for (int i = 0; i < 9; ++i) {
            const float* W9 = wt[i];
            float acc;
            if (i < 3)
                acc = a1[0][0]*W9[0] + a1[0][1]*W9[1] + a1[0][2]*W9[2]
                    + a1[1][0]*W9[3] + a1[1][1]*W9[4] + a1[1][2]*W9[5]
                    + a1[2][0]*W9[6] + a1[2][1]*W9[7] + a1[2][2]*W9[8];
            else if (i < 6)
                acc = a2[0][0]*W9[0] + a2[0][1]*W9[1] + a2[0][2]*W9[2]
                    + a2[1][0]*W9[3] + a2[1][1]*W9[4] + a2[1][2]*W9[5]
                    + a2[2][0]*W9[6] + a2[2][1]*W9[7] + a2[2][2]*W9[8];
            else
                acc = t3[0]*W9[0] + t3[1]*W9[1] + t3[2]*W9[2]
                    + t3[3]*W9[3] + t3[4]*W9[4] + t3[5]*W9[5]
                    + t3[6]*W9[6] + t3[7]*W9[7] + t3[8]*W9[8];
            sum[i] += acc;
            sq[i] = fmaf(acc, acc, sq[i]);
            dst[i][w * C_] = f2bf(acc);
        }
        // slide + prefetch next column (consumed next iteration)
        int wn = w0 + w + 2;
        bool wv = (w < 13) && (wn < W_);
#pragma unroll
        for (int dh = 0; dh < 3; ++dh) {
            a1[dh][0] = a1[dh][1]; a1[dh][1] = a1[dh][2];
            a2[dh][0] = a2[dh][1]; a2[dh][1] = a2[dh][2];
            int hh = h + dh - 1;
            float v1 = 0.f, v2 = 0.f;
            if (wv && hh >= 0 && hh < H_) {
                size_t off = (size_t)(hh * W_ + wn) * C_;
                v1 = pa[off]; v2 = pb[off];
            }
            a1[dh][2] = v1; a2[dh][2] = v2;
        }
    }
#pragma unroll
    for (int i = 0; i < 9; ++i) {
        atomicAdd(&part[(i * C_ + c) * 2],     sum[i]);
        atomicAdd(&part[(i * C_ + c) * 2 + 1], sq[i]);
    }
}

// ---------------------------------------------------------------------------
// Kernel 3: finalize folded BN affine from fused partials. grid (9), 384 thr.
// ---------------------------------------------------------------------------
__global__ void k_stats2(const float* __restrict__ part,
                         const float* __restrict__ gamma, const float* __restrict__ beta,
                         float* __restrict__ aScale, float* __restrict__ bShift) {
    int c = threadIdx.x;
    int idx = blockIdx.x;
    float s = part[(idx * C_ + c) * 2];
    float q = part[(idx * C_ + c) * 2 + 1];
    float mean = s / (float)BS_;
    float var  = q / (float)BS_ - mean * mean;
    float a = gamma[idx * C_ + c] * rsqrtf(var + EPS_);
    aScale[idx * C_ + c] = a;
    bShift[idx * C_ + c] = beta[idx * C_ + c] - mean * a;
}

// ---------------------------------------------------------------------------
// Kernel 4: combined weights. Wcb (bf16) [idx][o][c] = lin@pw * aScale[c];
// Bc[idx][o] = (lin@pw)@bShift + lin@pwb. Wave-shfl reduction.
// ---------------------------------------------------------------------------
__global__ void k_wcomb(const float* __restrict__ pw, const float* __restrict__ pwb,
                        const float* __restrict__ lin,
                        const float* __restrict__ aScale, const float* __restrict__ bShift,
                        u16* __restrict__ Wcb, float* __restrict__ Bc) {
    __shared__ float red[8];
    int og = blockIdx.x;            // 0..47
    int idx = blockIdx.y;           // 0..8
    int c = threadIdx.x;            // 0..383
    int wave = c >> 6, lane = c & 63;
    int li = (idx < 3) ? idx : 3 + (idx % 3);   // replicate branch-2 lin reuse bug
    float acc[8];
#pragma unroll
    for (int k = 0; k < 8; ++k) acc[k] = 0.f;
    const float* pwm = pw + (idx * C_) * C_ + c;
    const float* lb  = lin + ((li * C_) + og * 8) * C_;
    for (int m = 0; m < C_; ++m) {
        float pv = pwm[m * C_];
#pragma unroll
        for (int k = 0; k < 8; ++k)
            acc[k] += lb[k * C_ + m] * pv;
    }
    float aS = aScale[idx * C_ + c];
    float bS = bShift[idx * C_ + c];
    float pwbc = pwb[idx * C_ + c];
    for (int k = 0; k < 8; ++k) {
        int o = og * 8 + k;
        Wcb[(idx * C_ + o) * C_ + c] = f2bf(acc[k] * aS);
        float v = acc[k] * bS + lin[(li * C_ + o) * C_ + c] * pwbc;
#pragma unroll
        for (int msk = 1; msk < 64; msk <<= 1) v += __shfl_xor(v, msk);
        if (lane == 0) red[wave] = v;
        __syncthreads();
        if (c == 0)
            Bc[idx * C_ + o] = red[0] + red[1] + red[2] + red[3] + red[4] + red[5];
        __syncthreads();
    }
}

// ---------------------------------------------------------------------------
// Kernel 5: MFMA GEMM, zero LDS, manual 2-stage K prefetch.
// ---------------------------------------------------------------------------
__launch_bounds__(256)
__global__ void k_gemm(const u16* __restrict__ y, const u16* __restrict__ Wcb,
                       const float* __restrict__ Bc, u16* __restrict__ qkv) {
    int z = blockIdx.z;
    int idx = z >> 4, b = z & 15;
    int tid = threadIdx.x;
    int wave = tid >> 6;
    int lane = tid & 63;
    int lq = lane & 15;
    int quad = lane >> 4;
    int s_base = blockIdx.x * 128 + (wave >> 1) * 64;
    int o_base = blockIdx.y * 128 + (wave & 1) * 64;

    const u16* ybase = y + ((size_t)(idx * B_ + b) * S_) * C_;
    const u16* wbase = Wcb + (size_t)idx * C_ * C_;

    f32x4 acc[4][4];
#pragma unroll
    for (int i = 0; i < 4; ++i)
#pragma unroll
        for (int j = 0; j < 4; ++j) acc[i][j] = (f32x4){0.f,0.f,0.f,0.f};

    const u16* arow[4];
    const u16* brow[4];
#pragma unroll
    for (int mt = 0; mt < 4; ++mt) {
        int s = s_base + mt * 16 + lq; if (s > S_ - 1) s = S_ - 1;
        arow[mt] = ybase + (size_t)s * C_;
    }
#pragma unroll
    for (int nt = 0; nt < 4; ++nt) {
        int o = o_base + nt * 16 + lq;
        brow[nt] = wbase + (size_t)o * C_;
    }

    bf16x8 af[4], bw[4];
#pragma unroll
    for (int mt = 0; mt < 4; ++mt) af[mt] = *(const bf16x8*)(arow[mt] + quad * 8);
#pragma unroll
    for (int nt = 0; nt < 4; ++nt) bw[nt] = *(const bf16x8*)(brow[nt] + quad * 8);

#pragma unroll
    for (int ks = 0; ks < 12; ++ks) {
        bf16x8 afn[4], bwn[4];
        if (ks < 11) {
            int ko = (ks + 1) * 32 + quad * 8;
#pragma unroll
            for (int mt = 0; mt < 4; ++mt) afn[mt] = *(const bf16x8*)(arow[mt] + ko);
#pragma unroll
            for (int nt = 0; nt < 4; ++nt) bwn[nt] = *(const bf16x8*)(brow[nt] + ko);
        } else {
#pragma unroll
            for (int mt = 0; mt < 4; ++mt) afn[mt] = af[mt];
#pragma unroll
            for (int nt = 0; nt < 4; ++nt) bwn[nt] = bw[nt];
        }
#pragma unroll
        for (int mt = 0; mt < 4; ++mt)
#pragma unroll
            for (int nt = 0; nt < 4; ++nt)
                acc[mt][nt] = __builtin_amdgcn_mfma_f32_16x16x32_bf16(
                    af[mt], bw[nt], acc[mt][nt], 0, 0, 0);
#pragma unroll
        for (int mt = 0; mt < 4; ++mt) af[mt] = afn[mt];
#pragma unroll
        for (int nt = 0; nt < 4; ++nt) bw[nt] = bwn[nt];
    }

    float bias[4];
#pragma unroll
    for (int nt = 0; nt < 4; ++nt) bias[nt] = Bc[idx * C_ + o_base + nt * 16 + lq];
    u16* obase = qkv + ((size_t)(idx * B_ + b) * S_) * C_;
#pragma unroll
    for (int mt = 0; mt < 4; ++mt) {
#pragma unroll
        for (int r = 0; r < 4; ++r) {
            int s = s_base + mt * 16 + quad * 4 + r;
            if (s >= S_) continue;
            u16* row = obase + (size_t)s * C_ + o_base + lq;
#pragma unroll
            for (int nt = 0; nt < 4; ++nt)
                row[nt * 16] = f2bf(acc[mt][nt][r] + bias[nt]);
        }
    }
}

// ---------------------------------------------------------------------------
// Kernel 6: MFMA flash attention, M=32/wave, no-max softmax, T=64 chunks.
// Block = 4 waves = 128 Q-rows; 1D grid 2016 with XCD swizzle:
//   id = (zh&7) + 8*(qtile + 7*(zh>>3)) -> 7 qtile-blocks of one (z,h)
//   share an XCD (ids differ by 8) and are dispatch-adjacent -> K/V L2 reuse.
// 13 chunks of 64 t; LDS: V [64][68] u16 @0 (8B-aligned b64 rows, <=2-way
// banks), P per-wave [32][72] @4352+wave*2304 (16B-aligned b128 A-frags).
// Total 27136 B -> 5 blocks/CU (~62% occupancy).
// P reads via __builtin_memcpy (round-6 TBAA lesson); V reads typed but
// barrier-protected (R8-proven).
// ---------------------------------------------------------------------------
__launch_bounds__(256)
__global__ void k_attn(const u16* __restrict__ qkv, float* __restrict__ out) {
    __shared__ __align__(16) u16 sm[13568];   // V 4352 u16; P 4*2304 u16

    int id = blockIdx.x;
    int g8 = id & 7;
    int rest = id >> 3;             // 0..251
    int qtile = rest % 7;           // 0..6
    int zh = (rest / 7) * 8 + g8;   // 0..287
    int z = zh / 6, h = zh % 6;     // z: br*16+b
    int br = z >> 4;
    int tid = threadIdx.x;
    int wave = tid >> 6;
    int lane = tid & 63;
    int lq = lane & 15;
    int quad = lane >> 4;

    int idxq = 3 * br;
    const u16* qp = qkv + (size_t)((idxq * B_ + (z & 15)) * S_) * C_ + h * HD_;
    const u16* kp = qkv + (size_t)(((idxq + 1) * B_ + (z & 15)) * S_) * C_ + h * HD_;
    const u16* vp = qkv + (size_t)(((idxq + 2) * B_ + (z & 15)) * S_) * C_ + h * HD_;

    int qbase = qtile * 128 + wave * 32;
    int qrA = qbase + lq;      if (qrA > S_ - 1) qrA = S_ - 1;
    int qrB = qbase + 16 + lq; if (qrB > S_ - 1) qrB = S_ - 1;
    const u16* qpa = qp + (size_t)qrA * C_ + quad * 8;
    const u16* qpb = qp + (size_t)qrB * C_ + quad * 8;
    bf16x8 aqA0 = *(const bf16x8*)qpa;
    bf16x8 aqA1 = *(const bf16x8*)(qpa + 32);
    bf16x8 aqB0 = *(const bf16x8*)qpb;
    bf16x8 aqB1 = *(const bf16x8*)(qpb + 32);

    f32x4 oA[4], oB[4];
#pragma unroll
    for (int i = 0; i < 4; ++i) { oA[i] = (f32x4){0.f,0.f,0.f,0.f}; oB[i] = oA[i]; }
    float rsA[4] = {0.f,0.f,0.f,0.f}, rsB[4] = {0.f,0.f,0.f,0.f};

    // V staging: 2 consecutive t, 8 d per thread (256 thr cover 64t x 64d)
    int t2 = (tid & 31) * 2;        // 0..62
    int dg = (tid >> 5) * 8;        // 0..56
    int baseA = 4352 + wave * 2304; // P rows 0..15 (set A), stride 72
    int baseB = baseA + 16 * 72;    // P rows 16..31 (set B)

    for (int ch = 0; ch < 13; ++ch) {
        int tc = ch * 64;
        // ---- load V rows (issued pre-barrier for latency overlap)
        int tg0 = tc + t2;     if (tg0 > S_ - 1) tg0 = S_ - 1;
        int tg1 = tc + t2 + 1; if (tg1 > S_ - 1) tg1 = S_ - 1;
        bf16x8 v0 = *(const bf16x8*)(vp + (size_t)tg0 * C_ + dg);
        bf16x8 v1 = *(const bf16x8*)(vp + (size_t)tg1 * C_ + dg);
        __syncthreads();            // prior chunk's PV reads complete
#pragma unroll
        for (int e = 0; e < 8; ++e) {
            u32 pk = (u32)(u16)v0[e] | ((u32)(u16)v1[e] << 16);
            *(u32*)&sm[(dg + e) * 68 + t2] = pk;
        }
        __syncthreads();            // V visible to all waves

        // ---- QK^T + exp + P-store, per 16-t tile, both rowsets
#pragma unroll
        for (int tt = 0; tt < 4; ++tt) {
            bool live = (tc + tt * 16) < S_;    // wave-uniform (784 = 49*16)
            int tg = tc + tt * 16 + lq; if (tg > S_ - 1) tg = S_ - 1;
            const u16* kptr = kp + (size_t)tg * C_ + quad * 8;
            bf16x8 bk0 = *(const bf16x8*)kptr;
            bf16x8 bk1 = *(const bf16x8*)(kptr + 32);
            f32x4 sA = {0.f,0.f,0.f,0.f}, sB = sA;
            sA = __builtin_amdgcn_mfma_f32_16x16x32_bf16(aqA0, bk0, sA, 0, 0, 0);
            sA = __builtin_amdgcn_mfma_f32_16x16x32_bf16(aqA1, bk1, sA, 0, 0, 0);
            sB = __builtin_amdgcn_mfma_f32_16x16x32_bf16(aqB0, bk0, sB, 0, 0, 0);
            sB = __builtin_amdgcn_mfma_f32_16x16x32_bf16(aqB1, bk1, sB, 0, 0, 0);
#pragma unroll
            for (int r = 0; r < 4; ++r) {
                float pa = live ? __expf(sA[r] * SCALE_) : 0.f;
                float pb = live ? __expf(sB[r] * SCALE_) : 0.f;
                u16 pba = (u16)(__float_as_uint(pa) >> 16);   // trunc bf16
                u16 pbb = (u16)(__float_as_uint(pb) >> 16);
                sm[baseA + (quad * 4 + r) * 72 + tt * 16 + lq] = pba;
                sm[baseB + (quad * 4 + r) * 72 + tt * 16 + lq] = pbb;
                rsA[r] += __uint_as_float((u32)pba << 16);    // consistent w/ numerator
                rsB[r] += __uint_as_float((u32)pbb << 16);
            }
        }

        // ---- P A-frags (memcpy: byte-typed, ordered after u16 P-stores)
        bf16x8 apA[2], apB[2];
#pragma unroll
        for (int n = 0; n < 2; ++n) {
            __builtin_memcpy(&apA[n], &sm[baseA + lq * 72 + n * 32 + quad * 8], 16);
            __builtin_memcpy(&apB[n], &sm[baseB + lq * 72 + n * 32 + quad * 8], 16);
        }
        // ---- PV: V b64-pair frags from LDS, shared by both rowsets
        const char* bp = (const char*)sm;
#pragma unroll
        for (int dt = 0; dt < 4; ++dt) {
#pragma unroll
            for (int kh = 0; kh < 2; ++kh) {
                union { u64 q[2]; bf16x8 v; } bv;
                int j = (dt * 16 + lq) * 68 + kh * 32 + quad * 8;
                bv.q[0] = *(const u64*)(bp + 2 * j);
                bv.q[1] = *(const u64*)(bp + 2 * (j + 4));
                oA[dt] = __builtin_amdgcn_mfma_f32_16x16x32_bf16(apA[kh], bv.v, oA[dt], 0, 0, 0);
                oB[dt] = __builtin_amdgcn_mfma_f32_16x16x32_bf16(apB[kh], bv.v, oB[dt], 0, 0, 0);
            }
        }
    }

    // ---- final l reduction (once, 16-lane row groups)
#pragma unroll
    for (int msk = 1; msk <= 8; msk <<= 1)
#pragma unroll
        for (int r = 0; r < 4; ++r) {
            rsA[r] += __shfl_xor(rsA[r], msk);
            rsB[r] += __shfl_xor(rsB[r], msk);
        }

    // ---- epilogue
    size_t obase = ((size_t)z * NH_ + h) * S_ * HD_;
#pragma unroll
    for (int r = 0; r < 4; ++r) {
        int qa = qbase + quad * 4 + r;
        if (qa < S_) {
            float inv = 1.f / rsA[r];
            float* dst = out + obase + (size_t)qa * HD_ + lq;
            dst[0]  = oA[0][r] * inv;
            dst[16] = oA[1][r] * inv;
            dst[32] = oA[2][r] * inv;
            dst[48] = oA[3][r] * inv;
        }
        int qb = qbase + 16 + quad * 4 + r;
        if (qb < S_) {
            float inv = 1.f / rsB[r];
            float* dst = out + obase + (size_t)qb * HD_ + lq;
            dst[0]  = oB[0][r] * inv;
            dst[16] = oB[1][r] * inv;
            dst[32] = oB[2][r] * inv;
            dst[48] = oB[3][r] * inv;
        }
    }
}

// ---------------------------------------------------------------------------
extern "C" void kernel_launch(void* const* d_in, const int* in_sizes, int n_in,
                              void* d_out, int out_size, void* d_ws, size_t ws_size,
                              hipStream_t stream) {
    (void)in_sizes; (void)n_in; (void)out_size; (void)ws_size;
    const float* x1    = (const float*)d_in[0];
    const float* x2    = (const float*)d_in[3];
    const float* dw    = (const float*)d_in[6];
    const float* gamma = (const float*)d_in[7];
    const float* beta  = (const float*)d_in[8];
    const float* pw    = (const float*)d_in[9];
    const float* pwb   = (const float*)d_in[10];
    const float* lin   = (const float*)d_in[11];
    float* out = (float*)d_out;

    char* ws = (char*)d_ws;
    // ws layout (bytes):
    // y    bf16 [9][16][784][384]  @ 28901376   size 86,704,128
    // qkv  bf16 [9][16][784][384]  @ 115605504  size 86,704,128
    // Wcb  bf16 [9][384][384]      @ 202309632  size 2,654,208
    // Bc   f32  [9][384]           @ 204963840  size 13,824
    // aS   f32  [9][384]           @ 204977664  size 13,824
    // bS   f32  [9][384]           @ 204991488  size 13,824
    // part f32  [9][384][2]        @ 205005312  size 27,648 (memset to 0)
    u16*  y   = (u16*)(ws + 28901376);
    u16*  qkv = (u16*)(ws + 115605504);
    u16*  Wcb = (u16*)(ws + 202309632);
    float* Bc = (float*)(ws + 204963840);
    float* aS = (float*)(ws + 204977664);
    float* bS = (float*)(ws + 204991488);
    float* part = (float*)(ws + 205005312);

    hipMemsetAsync(part, 0, 9 * C_ * 2 * sizeof(float), stream);
    k_conv  <<<dim3(28, 16, 2), 384, 0, stream>>>(x1, x2, dw, y, part);
    k_stats2<<<dim3(9), 384, 0, stream>>>(part, gamma, beta, aS, bS);
    k_wcomb <<<dim3(48, 9), 384, 0, stream>>>(pw, pwb, lin, aS, bS, Wcb, Bc);
    k_gemm  <<<dim3(7, 3, 144), 256, 0, stream>>>(y, Wcb, Bc, qkv);
    k_attn  <<<dim3(2016), 256, 0, stream>>>(qkv, out);
}

// Round 2
// 524.784 us; speedup vs baseline: 1.1705x; 1.1705x over previous
//
#include <hip/hip_runtime.h>

typedef unsigned short u16;
typedef unsigned int u32;
typedef unsigned long long u64;

#define B_   16
#define C_   384
#define H_   28
#define W_   28
#define S_   784
#define NH_  6
#define HD_  64
#define BS_  (B_ * S_)            // 12544
#define SCALE_ 0.05103103630798288f  // 384^-0.5
#define EPS_ 1e-5f

typedef __attribute__((ext_vector_type(8))) short bf16x8;
typedef __attribute__((ext_vector_type(4))) float f32x4;

__device__ __forceinline__ float bf2f(u16 u) {
    return __uint_as_float(((u32)u) << 16);
}
__device__ __forceinline__ u16 f2bf(float f) {
    u32 x = __float_as_uint(f);
    u32 r = (x + 0x7fffu + ((x >> 16) & 1u)) >> 16;   // RNE
    return (u16)r;
}

// ---------------------------------------------------------------------------
// Kernel 2 (fused, 3-in-1 by input group): depthwise 3x3 conv for the 3 idx
// branches that share one input stream (g=0: idx0-2 from x1, g=1: idx3-5
// from x2, g=2: idx6-8 from x1+x2). One block = full 28-w row of one (h,b,g).
// 1D grid 1344 with XCD swizzle:
//   xcd=id&7, j=id>>3, p=xcd+8*(j/28), h=j%28, g=p/16, b=p%16
// -> blocks on one XCD are adjacent-h of the same (b,g) (3-row halo = L2 hit)
//    and each XCD owns g=0,1,2 for the same b-slices (x1[b]/x2[b] fetched ~once).
// Atomic profile identical to round-0 (3.1M ops, 448 sharers/addr) -- round-1's
// 9-way fusion doubled contention and WRITE_SIZE (109->219 MB).
// BN partial sums via atomicAdd into part[idx][c][2] (pre-zeroed).
// y[idx][b][s][c] bf16. Stats accumulated on pre-rounding f32.
// ---------------------------------------------------------------------------
__launch_bounds__(384)
__global__ void k_conv(const float* __restrict__ x1, const float* __restrict__ x2,
                       const float* __restrict__ dw, u16* __restrict__ y,
                       float* __restrict__ part) {
    int c = threadIdx.x;            // 0..383
    int id = blockIdx.x;            // 0..1343
    int xcd = id & 7;
    int j = id >> 3;                // 0..167
    int p = xcd + 8 * (j / 28);     // 0..47
    int h = j % 28;                 // 0..27
    int g = p / 16;                 // input group (wave-uniform)
    int b = p % 16;

    const float* pa = x1 + (size_t)b * S_ * C_ + c;
    const float* pb = x2 + (size_t)b * S_ * C_ + c;

    float wt[3][9];
#pragma unroll
    for (int i = 0; i < 3; ++i)
#pragma unroll
        for (int t = 0; t < 9; ++t)
            wt[i][t] = dw[((3 * g + i) * C_ + c) * 9 + t];

    // sliding window of the selected input (sum formed at load for g=2)
    float a[3][3];
#pragma unroll
    for (int dh = 0; dh < 3; ++dh) {
        int hh = h + dh - 1;
        bool hv = (hh >= 0) && (hh < H_);
        size_t o1 = (size_t)(hh * W_ + 0) * C_;
        size_t o2 = (size_t)(hh * W_ + 1) * C_;
        float v1 = 0.f, v2 = 0.f;
        if (hv) {
            if (g == 0)      { v1 = pa[o1];           v2 = pa[o2]; }
            else if (g == 1) { v1 = pb[o1];           v2 = pb[o2]; }
            else             { v1 = pa[o1] + pb[o1];  v2 = pa[o2] + pb[o2]; }
        }
        a[dh][0] = 0.f; a[dh][1] = v1; a[dh][2] = v2;
    }

    u16* dst[3];
#pragma unroll
    for (int i = 0; i < 3; ++i)
        dst[i] = y + ((size_t)((3 * g + i) * B_ + b) * S_ + h * W_) * C_ + c;

    float sum[3] = {0.f, 0.f, 0.f}, sq[3] = {0.f, 0.f, 0.f};

    for (int w = 0; w < W_; ++w) {
#pragma unroll
        for (int i = 0; i < 3; ++i) {
            const float* W9 = wt[i];
            float acc = a[0][0]*W9[0] + a[0][1]*W9[1] + a[0][2]*W9[2]
                      + a[1][0]*W9[3] + a[1][1]*W9[4] + a[1][2]*W9[5]
                      + a[2][0]*W9[6] + a[2][1]*W9[7] + a[2][2]*W9[8];
            sum[i] += acc;
            sq[i] = fmaf(acc, acc, sq[i]);
            dst[i][w * C_] = f2bf(acc);
        }
        // slide + prefetch next column (consumed next iteration)
        int wn = w + 2;
        bool wv = (wn < W_);
#pragma unroll
        for (int dh = 0; dh < 3; ++dh) {
            a[dh][0] = a[dh][1];
            a[dh][1] = a[dh][2];
            int hh = h + dh - 1;
            float v = 0.f;
            if (wv && hh >= 0 && hh < H_) {
                size_t off = (size_t)(hh * W_ + wn) * C_;
                if (g == 0)      v = pa[off];
                else if (g == 1) v = pb[off];
                else             v = pa[off] + pb[off];
            }
            a[dh][2] = v;
        }
    }
#pragma unroll
    for (int i = 0; i < 3; ++i) {
        atomicAdd(&part[((3 * g + i) * C_ + c) * 2],     sum[i]);
        atomicAdd(&part[((3 * g + i) * C_ + c) * 2 + 1], sq[i]);
    }
}

// ---------------------------------------------------------------------------
// Kernel 3: finalize folded BN affine from fused partials. grid (9), 384 thr.
// ---------------------------------------------------------------------------
__global__ void k_stats2(const float* __restrict__ part,
                         const float* __restrict__ gamma, const float* __restrict__ beta,
                         float* __restrict__ aScale, float* __restrict__ bShift) {
    int c = threadIdx.x;
    int idx = blockIdx.x;
    float s = part[(idx * C_ + c) * 2];
    float q = part[(idx * C_ + c) * 2 + 1];
    float mean = s / (float)BS_;
    float var  = q / (float)BS_ - mean * mean;
    float a = gamma[idx * C_ + c] * rsqrtf(var + EPS_);
    aScale[idx * C_ + c] = a;
    bShift[idx * C_ + c] = beta[idx * C_ + c] - mean * a;
}

// ---------------------------------------------------------------------------
// Kernel 4: combined weights. Wcb (bf16) [idx][o][c] = lin@pw * aScale[c];
// Bc[idx][o] = (lin@pw)@bShift + lin@pwb. Wave-shfl reduction.
// ---------------------------------------------------------------------------
__global__ void k_wcomb(const float* __restrict__ pw, const float* __restrict__ pwb,
                        const float* __restrict__ lin,
                        const float* __restrict__ aScale, const float* __restrict__ bShift,
                        u16* __restrict__ Wcb, float* __restrict__ Bc) {
    __shared__ float red[8];
    int og = blockIdx.x;            // 0..47
    int idx = blockIdx.y;           // 0..8
    int c = threadIdx.x;            // 0..383
    int wave = c >> 6, lane = c & 63;
    int li = (idx < 3) ? idx : 3 + (idx % 3);   // replicate branch-2 lin reuse bug
    float acc[8];
#pragma unroll
    for (int k = 0; k < 8; ++k) acc[k] = 0.f;
    const float* pwm = pw + (idx * C_) * C_ + c;
    const float* lb  = lin + ((li * C_) + og * 8) * C_;
    for (int m = 0; m < C_; ++m) {
        float pv = pwm[m * C_];
#pragma unroll
        for (int k = 0; k < 8; ++k)
            acc[k] += lb[k * C_ + m] * pv;
    }
    float aS = aScale[idx * C_ + c];
    float bS = bShift[idx * C_ + c];
    float pwbc = pwb[idx * C_ + c];
    for (int k = 0; k < 8; ++k) {
        int o = og * 8 + k;
        Wcb[(idx * C_ + o) * C_ + c] = f2bf(acc[k] * aS);
        float v = acc[k] * bS + lin[(li * C_ + o) * C_ + c] * pwbc;
#pragma unroll
        for (int msk = 1; msk < 64; msk <<= 1) v += __shfl_xor(v, msk);
        if (lane == 0) red[wave] = v;
        __syncthreads();
        if (c == 0)
            Bc[idx * C_ + o] = red[0] + red[1] + red[2] + red[3] + red[4] + red[5];
        __syncthreads();
    }
}

// ---------------------------------------------------------------------------
// Kernel 5: MFMA GEMM, zero LDS, manual 2-stage K prefetch.
// ---------------------------------------------------------------------------
__launch_bounds__(256)
__global__ void k_gemm(const u16* __restrict__ y, const u16* __restrict__ Wcb,
                       const float* __restrict__ Bc, u16* __restrict__ qkv) {
    int z = blockIdx.z;
    int idx = z >> 4, b = z & 15;
    int tid = threadIdx.x;
    int wave = tid >> 6;
    int lane = tid & 63;
    int lq = lane & 15;
    int quad = lane >> 4;
    int s_base = blockIdx.x * 128 + (wave >> 1) * 64;
    int o_base = blockIdx.y * 128 + (wave & 1) * 64;

    const u16* ybase = y + ((size_t)(idx * B_ + b) * S_) * C_;
    const u16* wbase = Wcb + (size_t)idx * C_ * C_;

    f32x4 acc[4][4];
#pragma unroll
    for (int i = 0; i < 4; ++i)
#pragma unroll
        for (int j = 0; j < 4; ++j) acc[i][j] = (f32x4){0.f,0.f,0.f,0.f};

    const u16* arow[4];
    const u16* brow[4];
#pragma unroll
    for (int mt = 0; mt < 4; ++mt) {
        int s = s_base + mt * 16 + lq; if (s > S_ - 1) s = S_ - 1;
        arow[mt] = ybase + (size_t)s * C_;
    }
#pragma unroll
    for (int nt = 0; nt < 4; ++nt) {
        int o = o_base + nt * 16 + lq;
        brow[nt] = wbase + (size_t)o * C_;
    }

    bf16x8 af[4], bw[4];
#pragma unroll
    for (int mt = 0; mt < 4; ++mt) af[mt] = *(const bf16x8*)(arow[mt] + quad * 8);
#pragma unroll
    for (int nt = 0; nt < 4; ++nt) bw[nt] = *(const bf16x8*)(brow[nt] + quad * 8);

#pragma unroll
    for (int ks = 0; ks < 12; ++ks) {
        bf16x8 afn[4], bwn[4];
        if (ks < 11) {
            int ko = (ks + 1) * 32 + quad * 8;
#pragma unroll
            for (int mt = 0; mt < 4; ++mt) afn[mt] = *(const bf16x8*)(arow[mt] + ko);
#pragma unroll
            for (int nt = 0; nt < 4; ++nt) bwn[nt] = *(const bf16x8*)(brow[nt] + ko);
        } else {
#pragma unroll
            for (int mt = 0; mt < 4; ++mt) afn[mt] = af[mt];
#pragma unroll
            for (int nt = 0; nt < 4; ++nt) bwn[nt] = bw[nt];
        }
#pragma unroll
        for (int mt = 0; mt < 4; ++mt)
#pragma unroll
            for (int nt = 0; nt < 4; ++nt)
                acc[mt][nt] = __builtin_amdgcn_mfma_f32_16x16x32_bf16(
                    af[mt], bw[nt], acc[mt][nt], 0, 0, 0);
#pragma unroll
        for (int mt = 0; mt < 4; ++mt) af[mt] = afn[mt];
#pragma unroll
        for (int nt = 0; nt < 4; ++nt) bw[nt] = bwn[nt];
    }

    float bias[4];
#pragma unroll
    for (int nt = 0; nt < 4; ++nt) bias[nt] = Bc[idx * C_ + o_base + nt * 16 + lq];
    u16* obase = qkv + ((size_t)(idx * B_ + b) * S_) * C_;
#pragma unroll
    for (int mt = 0; mt < 4; ++mt) {
#pragma unroll
        for (int r = 0; r < 4; ++r) {
            int s = s_base + mt * 16 + quad * 4 + r;
            if (s >= S_) continue;
            u16* row = obase + (size_t)s * C_ + o_base + lq;
#pragma unroll
            for (int nt = 0; nt < 4; ++nt)
                row[nt * 16] = f2bf(acc[mt][nt][r] + bias[nt]);
        }
    }
}

// ---------------------------------------------------------------------------
// Kernel 6: MFMA flash attention, M=32/wave, no-max softmax, T=64 chunks.
// Block = 4 waves = 128 Q-rows; 1D grid 2016 with XCD swizzle:
//   id = (zh&7) + 8*(qtile + 7*(zh>>3)) -> 7 qtile-blocks of one (z,h)
//   share an XCD (ids differ by 8) and are dispatch-adjacent -> K/V L2 reuse.
// 13 chunks of 64 t; LDS: V [64][68] u16 @0 (8B-aligned b64 rows, <=2-way
// banks), P per-wave [32][72] @4352+wave*2304 (16B-aligned b128 A-frags).
// Total 27136 B -> 5 blocks/CU (~62% occupancy).
// P reads via __builtin_memcpy (round-6 TBAA lesson); V reads typed but
// barrier-protected (R8-proven).
// ---------------------------------------------------------------------------
__launch_bounds__(256)
__global__ void k_attn(const u16* __restrict__ qkv, float* __restrict__ out) {
    __shared__ __align__(16) u16 sm[13568];   // V 4352 u16; P 4*2304 u16

    int id = blockIdx.x;
    int g8 = id & 7;
    int rest = id >> 3;             // 0..251
    int qtile = rest % 7;           // 0..6
    int zh = (rest / 7) * 8 + g8;   // 0..287
    int z = zh / 6, h = zh % 6;     // z: br*16+b
    int br = z >> 4;
    int tid = threadIdx.x;
    int wave = tid >> 6;
    int lane = tid & 63;
    int lq = lane & 15;
    int quad = lane >> 4;

    int idxq = 3 * br;
    const u16* qp = qkv + (size_t)((idxq * B_ + (z & 15)) * S_) * C_ + h * HD_;
    const u16* kp = qkv + (size_t)(((idxq + 1) * B_ + (z & 15)) * S_) * C_ + h * HD_;
    const u16* vp = qkv + (size_t)(((idxq + 2) * B_ + (z & 15)) * S_) * C_ + h * HD_;

    int qbase = qtile * 128 + wave * 32;
    int qrA = qbase + lq;      if (qrA > S_ - 1) qrA = S_ - 1;
    int qrB = qbase + 16 + lq; if (qrB > S_ - 1) qrB = S_ - 1;
    const u16* qpa = qp + (size_t)qrA * C_ + quad * 8;
    const u16* qpb = qp + (size_t)qrB * C_ + quad * 8;
    bf16x8 aqA0 = *(const bf16x8*)qpa;
    bf16x8 aqA1 = *(const bf16x8*)(qpa + 32);
    bf16x8 aqB0 = *(const bf16x8*)qpb;
    bf16x8 aqB1 = *(const bf16x8*)(qpb + 32);

    f32x4 oA[4], oB[4];
#pragma unroll
    for (int i = 0; i < 4; ++i) { oA[i] = (f32x4){0.f,0.f,0.f,0.f}; oB[i] = oA[i]; }
    float rsA[4] = {0.f,0.f,0.f,0.f}, rsB[4] = {0.f,0.f,0.f,0.f};

    // V staging: 2 consecutive t, 8 d per thread (256 thr cover 64t x 64d)
    int t2 = (tid & 31) * 2;        // 0..62
    int dg = (tid >> 5) * 8;        // 0..56
    int baseA = 4352 + wave * 2304; // P rows 0..15 (set A), stride 72
    int baseB = baseA + 16 * 72;    // P rows 16..31 (set B)

    for (int ch = 0; ch < 13; ++ch) {
        int tc = ch * 64;
        // ---- load V rows (issued pre-barrier for latency overlap)
        int tg0 = tc + t2;     if (tg0 > S_ - 1) tg0 = S_ - 1;
        int tg1 = tc + t2 + 1; if (tg1 > S_ - 1) tg1 = S_ - 1;
        bf16x8 v0 = *(const bf16x8*)(vp + (size_t)tg0 * C_ + dg);
        bf16x8 v1 = *(const bf16x8*)(vp + (size_t)tg1 * C_ + dg);
        __syncthreads();            // prior chunk's PV reads complete
#pragma unroll
        for (int e = 0; e < 8; ++e) {
            u32 pk = (u32)(u16)v0[e] | ((u32)(u16)v1[e] << 16);
            *(u32*)&sm[(dg + e) * 68 + t2] = pk;
        }
        __syncthreads();            // V visible to all waves

        // ---- QK^T + exp + P-store, per 16-t tile, both rowsets
#pragma unroll
        for (int tt = 0; tt < 4; ++tt) {
            bool live = (tc + tt * 16) < S_;    // wave-uniform (784 = 49*16)
            int tg = tc + tt * 16 + lq; if (tg > S_ - 1) tg = S_ - 1;
            const u16* kptr = kp + (size_t)tg * C_ + quad * 8;
            bf16x8 bk0 = *(const bf16x8*)kptr;
            bf16x8 bk1 = *(const bf16x8*)(kptr + 32);
            f32x4 sA = {0.f,0.f,0.f,0.f}, sB = sA;
            sA = __builtin_amdgcn_mfma_f32_16x16x32_bf16(aqA0, bk0, sA, 0, 0, 0);
            sA = __builtin_amdgcn_mfma_f32_16x16x32_bf16(aqA1, bk1, sA, 0, 0, 0);
            sB = __builtin_amdgcn_mfma_f32_16x16x32_bf16(aqB0, bk0, sB, 0, 0, 0);
            sB = __builtin_amdgcn_mfma_f32_16x16x32_bf16(aqB1, bk1, sB, 0, 0, 0);
#pragma unroll
            for (int r = 0; r < 4; ++r) {
                float pa = live ? __expf(sA[r] * SCALE_) : 0.f;
                float pb = live ? __expf(sB[r] * SCALE_) : 0.f;
                u16 pba = (u16)(__float_as_uint(pa) >> 16);   // trunc bf16
                u16 pbb = (u16)(__float_as_uint(pb) >> 16);
                sm[baseA + (quad * 4 + r) * 72 + tt * 16 + lq] = pba;
                sm[baseB + (quad * 4 + r) * 72 + tt * 16 + lq] = pbb;
                rsA[r] += __uint_as_float((u32)pba << 16);    // consistent w/ numerator
                rsB[r] += __uint_as_float((u32)pbb << 16);
            }
        }

        // ---- P A-frags (memcpy: byte-typed, ordered after u16 P-stores)
        bf16x8 apA[2], apB[2];
#pragma unroll
        for (int n = 0; n < 2; ++n) {
            __builtin_memcpy(&apA[n], &sm[baseA + lq * 72 + n * 32 + quad * 8], 16);
            __builtin_memcpy(&apB[n], &sm[baseB + lq * 72 + n * 32 + quad * 8], 16);
        }
        // ---- PV: V b64-pair frags from LDS, shared by both rowsets
        const char* bp = (const char*)sm;
#pragma unroll
        for (int dt = 0; dt < 4; ++dt) {
#pragma unroll
            for (int kh = 0; kh < 2; ++kh) {
                union { u64 q[2]; bf16x8 v; } bv;
                int j = (dt * 16 + lq) * 68 + kh * 32 + quad * 8;
                bv.q[0] = *(const u64*)(bp + 2 * j);
                bv.q[1] = *(const u64*)(bp + 2 * (j + 4));
                oA[dt] = __builtin_amdgcn_mfma_f32_16x16x32_bf16(apA[kh], bv.v, oA[dt], 0, 0, 0);
                oB[dt] = __builtin_amdgcn_mfma_f32_16x16x32_bf16(apB[kh], bv.v, oB[dt], 0, 0, 0);
            }
        }
    }

    // ---- final l reduction (once, 16-lane row groups)
#pragma unroll
    for (int msk = 1; msk <= 8; msk <<= 1)
#pragma unroll
        for (int r = 0; r < 4; ++r) {
            rsA[r] += __shfl_xor(rsA[r], msk);
            rsB[r] += __shfl_xor(rsB[r], msk);
        }

    // ---- epilogue
    size_t obase = ((size_t)z * NH_ + h) * S_ * HD_;
#pragma unroll
    for (int r = 0; r < 4; ++r) {
        int qa = qbase + quad * 4 + r;
        if (qa < S_) {
            float inv = 1.f / rsA[r];
            float* dst = out + obase + (size_t)qa * HD_ + lq;
            dst[0]  = oA[0][r] * inv;
            dst[16] = oA[1][r] * inv;
            dst[32] = oA[2][r] * inv;
            dst[48] = oA[3][r] * inv;
        }
        int qb = qbase + 16 + quad * 4 + r;
        if (qb < S_) {
            float inv = 1.f / rsB[r];
            float* dst = out + obase + (size_t)qb * HD_ + lq;
            dst[0]  = oB[0][r] * inv;
            dst[16] = oB[1][r] * inv;
            dst[32] = oB[2][r] * inv;
            dst[48] = oB[3][r] * inv;
        }
    }
}

// ---------------------------------------------------------------------------
extern "C" void kernel_launch(void* const* d_in, const int* in_sizes, int n_in,
                              void* d_out, int out_size, void* d_ws, size_t ws_size,
                              hipStream_t stream) {
    (void)in_sizes; (void)n_in; (void)out_size; (void)ws_size;
    const float* x1    = (const float*)d_in[0];
    const float* x2    = (const float*)d_in[3];
    const float* dw    = (const float*)d_in[6];
    const float* gamma = (const float*)d_in[7];
    const float* beta  = (const float*)d_in[8];
    const float* pw    = (const float*)d_in[9];
    const float* pwb   = (const float*)d_in[10];
    const float* lin   = (const float*)d_in[11];
    float* out = (float*)d_out;

    char* ws = (char*)d_ws;
    // ws layout (bytes):
    // y    bf16 [9][16][784][384]  @ 28901376   size 86,704,128
    // qkv  bf16 [9][16][784][384]  @ 115605504  size 86,704,128
    // Wcb  bf16 [9][384][384]      @ 202309632  size 2,654,208
    // Bc   f32  [9][384]           @ 204963840  size 13,824
    // aS   f32  [9][384]           @ 204977664  size 13,824
    // bS   f32  [9][384]           @ 204991488  size 13,824
    // part f32  [9][384][2]        @ 205005312  size 27,648 (memset to 0)
    u16*  y   = (u16*)(ws + 28901376);
    u16*  qkv = (u16*)(ws + 115605504);
    u16*  Wcb = (u16*)(ws + 202309632);
    float* Bc = (float*)(ws + 204963840);
    float* aS = (float*)(ws + 204977664);
    float* bS = (float*)(ws + 204991488);
    float* part = (float*)(ws + 205005312);

    hipMemsetAsync(part, 0, 9 * C_ * 2 * sizeof(float), stream);
    k_conv  <<<dim3(1344), 384, 0, stream>>>(x1, x2, dw, y, part);
    k_stats2<<<dim3(9), 384, 0, stream>>>(part, gamma, beta, aS, bS);
    k_wcomb <<<dim3(48, 9), 384, 0, stream>>>(pw, pwb, lin, aS, bS, Wcb, Bc);
    k_gemm  <<<dim3(7, 3, 144), 256, 0, stream>>>(y, Wcb, Bc, qkv);
    k_attn  <<<dim3(2016), 256, 0, stream>>>(qkv, out);
}

// Round 3
// 448.945 us; speedup vs baseline: 1.3682x; 1.1689x over previous
//
#include <hip/hip_runtime.h>

typedef unsigned short u16;
typedef unsigned int u32;
typedef unsigned long long u64;

#define B_   16
#define C_   384
#define H_   28
#define W_   28
#define S_   784
#define NH_  6
#define HD_  64
#define BS_  (B_ * S_)            // 12544
#define SCALE_ 0.05103103630798288f  // 384^-0.5
#define EPS_ 1e-5f

typedef __attribute__((ext_vector_type(8))) short bf16x8;
typedef __attribute__((ext_vector_type(4))) float f32x4;

__device__ __forceinline__ float bf2f(u16 u) {
    return __uint_as_float(((u32)u) << 16);
}
__device__ __forceinline__ u16 f2bf(float f) {
    u32 x = __float_as_uint(f);
    u32 r = (x + 0x7fffu + ((x >> 16) & 1u)) >> 16;   // RNE
    return (u16)r;
}

// async global->LDS 16B per lane; dest = wave-uniform base + lane*16 (HW rule)
__device__ __forceinline__ void gld16(const u16* g, u16* l) {
    __builtin_amdgcn_global_load_lds(
        (__attribute__((address_space(1))) void*)g,
        (__attribute__((address_space(3))) void*)l, 16, 0, 0);
}

// ---------------------------------------------------------------------------
// Kernel 2 (fused, 3-in-1 by input group): depthwise 3x3 conv for the 3 idx
// branches that share one input stream (g=0: idx0-2 from x1, g=1: idx3-5
// from x2, g=2: idx6-8 from x1+x2). One block = full 28-w row of one (h,b,g).
// 1D grid 1344 with XCD swizzle (adjacent-h same (b,g) share an XCD -> L2).
// ---------------------------------------------------------------------------
__launch_bounds__(384)
__global__ void k_conv(const float* __restrict__ x1, const float* __restrict__ x2,
                       const float* __restrict__ dw, u16* __restrict__ y,
                       float* __restrict__ part) {
    int c = threadIdx.x;            // 0..383
    int id = blockIdx.x;            // 0..1343
    int xcd = id & 7;
    int j = id >> 3;                // 0..167
    int p = xcd + 8 * (j / 28);     // 0..47
    int h = j % 28;                 // 0..27
    int g = p / 16;                 // input group (wave-uniform)
    int b = p % 16;

    const float* pa = x1 + (size_t)b * S_ * C_ + c;
    const float* pb = x2 + (size_t)b * S_ * C_ + c;

    float wt[3][9];
#pragma unroll
    for (int i = 0; i < 3; ++i)
#pragma unroll
        for (int t = 0; t < 9; ++t)
            wt[i][t] = dw[((3 * g + i) * C_ + c) * 9 + t];

    // sliding window of the selected input (sum formed at load for g=2)
    float a[3][3];
#pragma unroll
    for (int dh = 0; dh < 3; ++dh) {
        int hh = h + dh - 1;
        bool hv = (hh >= 0) && (hh < H_);
        size_t o1 = (size_t)(hh * W_ + 0) * C_;
        size_t o2 = (size_t)(hh * W_ + 1) * C_;
        float v1 = 0.f, v2 = 0.f;
        if (hv) {
            if (g == 0)      { v1 = pa[o1];           v2 = pa[o2]; }
            else if (g == 1) { v1 = pb[o1];           v2 = pb[o2]; }
            else             { v1 = pa[o1] + pb[o1];  v2 = pa[o2] + pb[o2]; }
        }
        a[dh][0] = 0.f; a[dh][1] = v1; a[dh][2] = v2;
    }

    u16* dst[3];
#pragma unroll
    for (int i = 0; i < 3; ++i)
        dst[i] = y + ((size_t)((3 * g + i) * B_ + b) * S_ + h * W_) * C_ + c;

    float sum[3] = {0.f, 0.f, 0.f}, sq[3] = {0.f, 0.f, 0.f};

    for (int w = 0; w < W_; ++w) {
#pragma unroll
        for (int i = 0; i < 3; ++i) {
            const float* W9 = wt[i];
            float acc = a[0][0]*W9[0] + a[0][1]*W9[1] + a[0][2]*W9[2]
                      + a[1][0]*W9[3] + a[1][1]*W9[4] + a[1][2]*W9[5]
                      + a[2][0]*W9[6] + a[2][1]*W9[7] + a[2][2]*W9[8];
            sum[i] += acc;
            sq[i] = fmaf(acc, acc, sq[i]);
            dst[i][w * C_] = f2bf(acc);
        }
        // slide + prefetch next column (consumed next iteration)
        int wn = w + 2;
        bool wv = (wn < W_);
#pragma unroll
        for (int dh = 0; dh < 3; ++dh) {
            a[dh][0] = a[dh][1];
            a[dh][1] = a[dh][2];
            int hh = h + dh - 1;
            float v = 0.f;
            if (wv && hh >= 0 && hh < H_) {
                size_t off = (size_t)(hh * W_ + wn) * C_;
                if (g == 0)      v = pa[off];
                else if (g == 1) v = pb[off];
                else             v = pa[off] + pb[off];
            }
            a[dh][2] = v;
        }
    }
#pragma unroll
    for (int i = 0; i < 3; ++i) {
        atomicAdd(&part[((3 * g + i) * C_ + c) * 2],     sum[i]);
        atomicAdd(&part[((3 * g + i) * C_ + c) * 2 + 1], sq[i]);
    }
}

// ---------------------------------------------------------------------------
// Kernel 3: finalize folded BN affine from fused partials. grid (9), 384 thr.
// ---------------------------------------------------------------------------
__global__ void k_stats2(const float* __restrict__ part,
                         const float* __restrict__ gamma, const float* __restrict__ beta,
                         float* __restrict__ aScale, float* __restrict__ bShift) {
    int c = threadIdx.x;
    int idx = blockIdx.x;
    float s = part[(idx * C_ + c) * 2];
    float q = part[(idx * C_ + c) * 2 + 1];
    float mean = s / (float)BS_;
    float var  = q / (float)BS_ - mean * mean;
    float a = gamma[idx * C_ + c] * rsqrtf(var + EPS_);
    aScale[idx * C_ + c] = a;
    bShift[idx * C_ + c] = beta[idx * C_ + c] - mean * a;
}

// ---------------------------------------------------------------------------
// Kernel 4: combined weights. Wcb (bf16) [idx][o][c] = lin@pw * aScale[c];
// Bc[idx][o] = (lin@pw)@bShift + lin@pwb. Wave-shfl reduction.
// ---------------------------------------------------------------------------
__global__ void k_wcomb(const float* __restrict__ pw, const float* __restrict__ pwb,
                        const float* __restrict__ lin,
                        const float* __restrict__ aScale, const float* __restrict__ bShift,
                        u16* __restrict__ Wcb, float* __restrict__ Bc) {
    __shared__ float red[8];
    int og = blockIdx.x;            // 0..47
    int idx = blockIdx.y;           // 0..8
    int c = threadIdx.x;            // 0..383
    int wave = c >> 6, lane = c & 63;
    int li = (idx < 3) ? idx : 3 + (idx % 3);   // replicate branch-2 lin reuse bug
    float acc[8];
#pragma unroll
    for (int k = 0; k < 8; ++k) acc[k] = 0.f;
    const float* pwm = pw + (idx * C_) * C_ + c;
    const float* lb  = lin + ((li * C_) + og * 8) * C_;
    for (int m = 0; m < C_; ++m) {
        float pv = pwm[m * C_];
#pragma unroll
        for (int k = 0; k < 8; ++k)
            acc[k] += lb[k * C_ + m] * pv;
    }
    float aS = aScale[idx * C_ + c];
    float bS = bShift[idx * C_ + c];
    float pwbc = pwb[idx * C_ + c];
    for (int k = 0; k < 8; ++k) {
        int o = og * 8 + k;
        Wcb[(idx * C_ + o) * C_ + c] = f2bf(acc[k] * aS);
        float v = acc[k] * bS + lin[(li * C_ + o) * C_ + c] * pwbc;
#pragma unroll
        for (int msk = 1; msk < 64; msk <<= 1) v += __shfl_xor(v, msk);
        if (lane == 0) red[wave] = v;
        __syncthreads();
        if (c == 0)
            Bc[idx * C_ + o] = red[0] + red[1] + red[2] + red[3] + red[4] + red[5];
        __syncthreads();
    }
}

// ---------------------------------------------------------------------------
// Kernel 5: MFMA GEMM, m97 structure: 128x128 tile, BK=32, double-buffered
// LDS staged via global_load_lds(16B), 1 barrier per K-step.
// Source-side XOR chunk swizzle q ^= (r ^ (r>>2)) & 3 (both-sides, rule 21)
// keeps ds_read_b128 bank conflicts ~2-way on 64B LDS rows.
// 1D grid 3024, z-clustered XCD swizzle: all 21 (bx,by) blocks of one z land
// consecutive on one XCD -> A(602KB)+B(295KB) L2-resident, re-reads are hits.
// ---------------------------------------------------------------------------
__launch_bounds__(256)
__global__ void k_gemm(const u16* __restrict__ y, const u16* __restrict__ Wcb,
                       const float* __restrict__ Bc, u16* __restrict__ qkv) {
    __shared__ __align__(16) u16 ldsA[2][4096];   // [stage][128 rows][4 chunks*8]
    __shared__ __align__(16) u16 ldsB[2][4096];

    int id = blockIdx.x;            // 0..3023
    int xcd = id & 7;
    int kb = id >> 3;               // 0..377
    int zz = kb / 21;               // 0..17
    int t  = kb % 21;
    int z  = zz * 8 + xcd;          // 0..143
    int by = t / 7, bx = t % 7;
    int idx = z >> 4, b = z & 15;

    int tid = threadIdx.x;
    int wave = tid >> 6;
    int lane = tid & 63;
    int lq = lane & 15;
    int quad = lane >> 4;
    int o_base = by * 128 + (wave & 1) * 64;          // for bias/epilogue
    int s_base_w = bx * 128 + (wave >> 1) * 64;       // for epilogue

    const u16* ybase = y + (size_t)(idx * B_ + b) * S_ * C_;
    const u16* wbase = Wcb + (size_t)idx * C_ * C_;

    // staging geometry: element e = i*256+tid covers 16B; row r=e>>2, chunk q=e&3
    int r0 = tid >> 2;              // issue-0 row (0..63); issue-1 adds 64
    int qs = (tid & 3) ^ ((r0 ^ (r0 >> 2)) & 3);   // swizzle invariant under +64
    int srA0 = bx * 128 + r0;       if (srA0 > S_ - 1) srA0 = S_ - 1;
    int srA1 = bx * 128 + r0 + 64;  if (srA1 > S_ - 1) srA1 = S_ - 1;
    const u16* gA0 = ybase + (size_t)srA0 * C_ + qs * 8;
    const u16* gA1 = ybase + (size_t)srA1 * C_ + qs * 8;
    const u16* gB0 = wbase + (size_t)(by * 128 + r0) * C_ + qs * 8;
    const u16* gB1 = wbase + (size_t)(by * 128 + r0 + 64) * C_ + qs * 8;
    int lo0 = wave * 512;           // u16 idx: wave base, issue 0
    int lo1 = 2048 + wave * 512;    // issue 1

#define STAGE(stg, kk) do {                          \
        gld16(gA0 + (kk) * 32, &ldsA[stg][lo0]);     \
        gld16(gA1 + (kk) * 32, &ldsA[stg][lo1]);     \
        gld16(gB0 + (kk) * 32, &ldsB[stg][lo0]);     \
        gld16(gB1 + (kk) * 32, &ldsB[stg][lo1]);     \
    } while (0)

    f32x4 acc[4][4];
#pragma unroll
    for (int i = 0; i < 4; ++i)
#pragma unroll
        for (int j = 0; j < 4; ++j) acc[i][j] = (f32x4){0.f,0.f,0.f,0.f};

    STAGE(0, 0);
    __syncthreads();

    int qoff = (quad ^ ((lq ^ (lq >> 2)) & 3)) * 8;   // read-side swizzle
    bf16x8 af[4], bw[4];
#pragma unroll
    for (int ks = 0; ks < 12; ++ks) {
        int cur = ks & 1;
        if (ks < 11) STAGE(cur ^ 1, ks + 1);          // async into other buffer
#pragma unroll
        for (int mt = 0; mt < 4; ++mt) {
            int sl = (wave >> 1) * 64 + mt * 16 + lq;
            __builtin_memcpy(&af[mt], &ldsA[cur][sl * 32 + qoff], 16);
        }
#pragma unroll
        for (int nt = 0; nt < 4; ++nt) {
            int ol = (wave & 1) * 64 + nt * 16 + lq;
            __builtin_memcpy(&bw[nt], &ldsB[cur][ol * 32 + qoff], 16);
        }
#pragma unroll
        for (int mt = 0; mt < 4; ++mt)
#pragma unroll
            for (int nt = 0; nt < 4; ++nt)
                acc[mt][nt] = __builtin_amdgcn_mfma_f32_16x16x32_bf16(
                    af[mt], bw[nt], acc[mt][nt], 0, 0, 0);
        __syncthreads();    // drains this step's stage (vmcnt) + frees cur buf
    }
#undef STAGE

    float bias[4];
#pragma unroll
    for (int nt = 0; nt < 4; ++nt) bias[nt] = Bc[idx * C_ + o_base + nt * 16 + lq];
    u16* obase = qkv + ((size_t)(idx * B_ + b) * S_) * C_;
#pragma unroll
    for (int mt = 0; mt < 4; ++mt) {
#pragma unroll
        for (int r = 0; r < 4; ++r) {
            int s = s_base_w + mt * 16 + quad * 4 + r;
            if (s >= S_) continue;
            u16* row = obase + (size_t)s * C_ + o_base + lq;
#pragma unroll
            for (int nt = 0; nt < 4; ++nt)
                row[nt * 16] = f2bf(acc[mt][nt][r] + bias[nt]);
        }
    }
}

// ---------------------------------------------------------------------------
// Kernel 6: MFMA flash attention, M=32/wave, no-max softmax, T=64 chunks.
// Block = 4 waves = 128 Q-rows; 1D grid 2016 with XCD swizzle:
//   id = (zh&7) + 8*(qtile + 7*(zh>>3)) -> 7 qtile-blocks of one (z,h)
//   share an XCD (ids differ by 8) and are dispatch-adjacent -> K/V L2 reuse.
// 13 chunks of 64 t; LDS: V [64][68] u16 @0 (8B-aligned b64 rows, <=2-way
// banks), P per-wave [32][72] @4352+wave*2304 (16B-aligned b128 A-frags).
// Total 27136 B -> 5 blocks/CU (~62% occupancy).
// P reads via __builtin_memcpy (round-6 TBAA lesson); V reads typed but
// barrier-protected (R8-proven).
// ---------------------------------------------------------------------------
__launch_bounds__(256)
__global__ void k_attn(const u16* __restrict__ qkv, float* __restrict__ out) {
    __shared__ __align__(16) u16 sm[13568];   // V 4352 u16; P 4*2304 u16

    int id = blockIdx.x;
    int g8 = id & 7;
    int rest = id >> 3;             // 0..251
    int qtile = rest % 7;           // 0..6
    int zh = (rest / 7) * 8 + g8;   // 0..287
    int z = zh / 6, h = zh % 6;     // z: br*16+b
    int br = z >> 4;
    int tid = threadIdx.x;
    int wave = tid >> 6;
    int lane = tid & 63;
    int lq = lane & 15;
    int quad = lane >> 4;

    int idxq = 3 * br;
    const u16* qp = qkv + (size_t)((idxq * B_ + (z & 15)) * S_) * C_ + h * HD_;
    const u16* kp = qkv + (size_t)(((idxq + 1) * B_ + (z & 15)) * S_) * C_ + h * HD_;
    const u16* vp = qkv + (size_t)(((idxq + 2) * B_ + (z & 15)) * S_) * C_ + h * HD_;

    int qbase = qtile * 128 + wave * 32;
    int qrA = qbase + lq;      if (qrA > S_ - 1) qrA = S_ - 1;
    int qrB = qbase + 16 + lq; if (qrB > S_ - 1) qrB = S_ - 1;
    const u16* qpa = qp + (size_t)qrA * C_ + quad * 8;
    const u16* qpb = qp + (size_t)qrB * C_ + quad * 8;
    bf16x8 aqA0 = *(const bf16x8*)qpa;
    bf16x8 aqA1 = *(const bf16x8*)(qpa + 32);
    bf16x8 aqB0 = *(const bf16x8*)qpb;
    bf16x8 aqB1 = *(const bf16x8*)(qpb + 32);

    f32x4 oA[4], oB[4];
#pragma unroll
    for (int i = 0; i < 4; ++i) { oA[i] = (f32x4){0.f,0.f,0.f,0.f}; oB[i] = oA[i]; }
    float rsA[4] = {0.f,0.f,0.f,0.f}, rsB[4] = {0.f,0.f,0.f,0.f};

    // V staging: 2 consecutive t, 8 d per thread (256 thr cover 64t x 64d)
    int t2 = (tid & 31) * 2;        // 0..62
    int dg = (tid >> 5) * 8;        // 0..56
    int baseA = 4352 + wave * 2304; // P rows 0..15 (set A), stride 72
    int baseB = baseA + 16 * 72;    // P rows 16..31 (set B)

    for (int ch = 0; ch < 13; ++ch) {
        int tc = ch * 64;
        // ---- load V rows (issued pre-barrier for latency overlap)
        int tg0 = tc + t2;     if (tg0 > S_ - 1) tg0 = S_ - 1;
        int tg1 = tc + t2 + 1; if (tg1 > S_ - 1) tg1 = S_ - 1;
        bf16x8 v0 = *(const bf16x8*)(vp + (size_t)tg0 * C_ + dg);
        bf16x8 v1 = *(const bf16x8*)(vp + (size_t)tg1 * C_ + dg);
        __syncthreads();            // prior chunk's PV reads complete
#pragma unroll
        for (int e = 0; e < 8; ++e) {
            u32 pk = (u32)(u16)v0[e] | ((u32)(u16)v1[e] << 16);
            *(u32*)&sm[(dg + e) * 68 + t2] = pk;
        }
        __syncthreads();            // V visible to all waves

        // ---- QK^T + exp + P-store, per 16-t tile, both rowsets
#pragma unroll
        for (int tt = 0; tt < 4; ++tt) {
            bool live = (tc + tt * 16) < S_;    // wave-uniform (784 = 49*16)
            int tg = tc + tt * 16 + lq; if (tg > S_ - 1) tg = S_ - 1;
            const u16* kptr = kp + (size_t)tg * C_ + quad * 8;
            bf16x8 bk0 = *(const bf16x8*)kptr;
            bf16x8 bk1 = *(const bf16x8*)(kptr + 32);
            f32x4 sA = {0.f,0.f,0.f,0.f}, sB = sA;
            sA = __builtin_amdgcn_mfma_f32_16x16x32_bf16(aqA0, bk0, sA, 0, 0, 0);
            sA = __builtin_amdgcn_mfma_f32_16x16x32_bf16(aqA1, bk1, sA, 0, 0, 0);
            sB = __builtin_amdgcn_mfma_f32_16x16x32_bf16(aqB0, bk0, sB, 0, 0, 0);
            sB = __builtin_amdgcn_mfma_f32_16x16x32_bf16(aqB1, bk1, sB, 0, 0, 0);
#pragma unroll
            for (int r = 0; r < 4; ++r) {
                float pa = live ? __expf(sA[r] * SCALE_) : 0.f;
                float pb = live ? __expf(sB[r] * SCALE_) : 0.f;
                u16 pba = (u16)(__float_as_uint(pa) >> 16);   // trunc bf16
                u16 pbb = (u16)(__float_as_uint(pb) >> 16);
                sm[baseA + (quad * 4 + r) * 72 + tt * 16 + lq] = pba;
                sm[baseB + (quad * 4 + r) * 72 + tt * 16 + lq] = pbb;
                rsA[r] += __uint_as_float((u32)pba << 16);    // consistent w/ numerator
                rsB[r] += __uint_as_float((u32)pbb << 16);
            }
        }

        // ---- P A-frags (memcpy: byte-typed, ordered after u16 P-stores)
        bf16x8 apA[2], apB[2];
#pragma unroll
        for (int n = 0; n < 2; ++n) {
            __builtin_memcpy(&apA[n], &sm[baseA + lq * 72 + n * 32 + quad * 8], 16);
            __builtin_memcpy(&apB[n], &sm[baseB + lq * 72 + n * 32 + quad * 8], 16);
        }
        // ---- PV: V b64-pair frags from LDS, shared by both rowsets
        const char* bp = (const char*)sm;
#pragma unroll
        for (int dt = 0; dt < 4; ++dt) {
#pragma unroll
            for (int kh = 0; kh < 2; ++kh) {
                union { u64 q[2]; bf16x8 v; } bv;
                int j = (dt * 16 + lq) * 68 + kh * 32 + quad * 8;
                bv.q[0] = *(const u64*)(bp + 2 * j);
                bv.q[1] = *(const u64*)(bp + 2 * (j + 4));
                oA[dt] = __builtin_amdgcn_mfma_f32_16x16x32_bf16(apA[kh], bv.v, oA[dt], 0, 0, 0);
                oB[dt] = __builtin_amdgcn_mfma_f32_16x16x32_bf16(apB[kh], bv.v, oB[dt], 0, 0, 0);
            }
        }
    }

    // ---- final l reduction (once, 16-lane row groups)
#pragma unroll
    for (int msk = 1; msk <= 8; msk <<= 1)
#pragma unroll
        for (int r = 0; r < 4; ++r) {
            rsA[r] += __shfl_xor(rsA[r], msk);
            rsB[r] += __shfl_xor(rsB[r], msk);
        }

    // ---- epilogue
    size_t obase = ((size_t)z * NH_ + h) * S_ * HD_;
#pragma unroll
    for (int r = 0; r < 4; ++r) {
        int qa = qbase + quad * 4 + r;
        if (qa < S_) {
            float inv = 1.f / rsA[r];
            float* dst = out + obase + (size_t)qa * HD_ + lq;
            dst[0]  = oA[0][r] * inv;
            dst[16] = oA[1][r] * inv;
            dst[32] = oA[2][r] * inv;
            dst[48] = oA[3][r] * inv;
        }
        int qb = qbase + 16 + quad * 4 + r;
        if (qb < S_) {
            float inv = 1.f / rsB[r];
            float* dst = out + obase + (size_t)qb * HD_ + lq;
            dst[0]  = oB[0][r] * inv;
            dst[16] = oB[1][r] * inv;
            dst[32] = oB[2][r] * inv;
            dst[48] = oB[3][r] * inv;
        }
    }
}

// ---------------------------------------------------------------------------
extern "C" void kernel_launch(void* const* d_in, const int* in_sizes, int n_in,
                              void* d_out, int out_size, void* d_ws, size_t ws_size,
                              hipStream_t stream) {
    (void)in_sizes; (void)n_in; (void)out_size; (void)ws_size;
    const float* x1    = (const float*)d_in[0];
    const float* x2    = (const float*)d_in[3];
    const float* dw    = (const float*)d_in[6];
    const float* gamma = (const float*)d_in[7];
    const float* beta  = (const float*)d_in[8];
    const float* pw    = (const float*)d_in[9];
    const float* pwb   = (const float*)d_in[10];
    const float* lin   = (const float*)d_in[11];
    float* out = (float*)d_out;

    char* ws = (char*)d_ws;
    // ws layout (bytes):
    // y    bf16 [9][16][784][384]  @ 28901376   size 86,704,128
    // qkv  bf16 [9][16][784][384]  @ 115605504  size 86,704,128
    // Wcb  bf16 [9][384][384]      @ 202309632  size 2,654,208
    // Bc   f32  [9][384]           @ 204963840  size 13,824
    // aS   f32  [9][384]           @ 204977664  size 13,824
    // bS   f32  [9][384]           @ 204991488  size 13,824
    // part f32  [9][384][2]        @ 205005312  size 27,648 (memset to 0)
    u16*  y   = (u16*)(ws + 28901376);
    u16*  qkv = (u16*)(ws + 115605504);
    u16*  Wcb = (u16*)(ws + 202309632);
    float* Bc = (float*)(ws + 204963840);
    float* aS = (float*)(ws + 204977664);
    float* bS = (float*)(ws + 204991488);
    float* part = (float*)(ws + 205005312);

    hipMemsetAsync(part, 0, 9 * C_ * 2 * sizeof(float), stream);
    k_conv  <<<dim3(1344), 384, 0, stream>>>(x1, x2, dw, y, part);
    k_stats2<<<dim3(9), 384, 0, stream>>>(part, gamma, beta, aS, bS);
    k_wcomb <<<dim3(48, 9), 384, 0, stream>>>(pw, pwb, lin, aS, bS, Wcb, Bc);
    k_gemm  <<<dim3(3024), 256, 0, stream>>>(y, Wcb, Bc, qkv);
    k_attn  <<<dim3(2016), 256, 0, stream>>>(qkv, out);
}